// Round 3
// baseline (257.478 us; speedup 1.0000x reference)
//
#include <hip/hip_runtime.h>
#include <hip/hip_bf16.h>

// loss = mean_n( logsumexp([pos_n, (online@queue)_n]/t) - pos_n/t )   (fwd: alpha mix = identity)
// v3: single fused GEMM (transpose folded into B-staging, full-K B in LDS, A frags from global,
//     ONE barrier per block, base-2 softmax), finalize with atomic mean.

#define NROWS 1024
#define DDIM  256
#define KQ    65536
#define BN    128
#define NPART 1024
#define LN2_F 0.69314718055994531f

typedef short  short8  __attribute__((ext_vector_type(8)));
typedef float  floatx4 __attribute__((ext_vector_type(4)));

__device__ __forceinline__ unsigned short f2bf(float f) {
    unsigned int u = __float_as_uint(f);
    u += 0x7FFFu + ((u >> 16) & 1u);   // RNE
    return (unsigned short)(u >> 16);
}

// ---- A conversion: bf16(A / (t*ln2)) -> GEMM accumulators are base-2 logits ----
__global__ __launch_bounds__(256)
void conv_a(const float* __restrict__ A, const float* __restrict__ temp,
            unsigned short* __restrict__ Ab)
{
    const float s = 1.0f / (temp[0] * LN2_F);
    const int i = blockIdx.x * 256 + threadIdx.x;       // 65536 threads, 1 float4 each
    const float4 v = ((const float4*)A)[i];
    ushort4 w;
    w.x = f2bf(v.x * s); w.y = f2bf(v.y * s);
    w.z = f2bf(v.z * s); w.w = f2bf(v.w * s);
    ((ushort4*)Ab)[i] = w;
}

// ---- fused GEMM + online-softmax partials. Grid: 512 blocks (one 128-col stripe each) ----
__global__ __launch_bounds__(512, 4)
void gemm_softmax(const unsigned short* __restrict__ Ab,   // [1024][256] bf16, pre-scaled
                  const float* __restrict__ Q,             // [256][65536] fp32
                  float2* __restrict__ partials)           // [1024][NPART]
{
    __shared__ __align__(16) unsigned short Bl[BN * DDIM];   // [n][k] bf16, 64 KB, swizzled

    const int tid  = threadIdx.x;
    const int lane = tid & 63;
    const int wave = tid >> 6;          // 0..7
    const int wc   = wave & 1;          // 64-col band
    const int wr   = wave >> 1;         // 0..3 row-wave
    const int l15  = lane & 15;
    const int quad = lane >> 4;
    const int nb   = blockIdx.x;        // 0..511
    const int nbase = nb * BN;

    // ---- stage B once: Q[k][nbase..+127] fp32 -> Bl[n][k] bf16 (register transpose) ----
    #pragma unroll
    for (int iter = 0; iter < 2; ++iter) {
        const int t2 = iter * 512 + tid;
        const int ny = t2 & 31;          // n-quad (4 cols)
        const int ko = t2 >> 5;          // k-octet (8 rows), 0..31
        float4 v[8];
        #pragma unroll
        for (int j = 0; j < 8; ++j)
            v[j] = *(const float4*)(Q + (size_t)(ko * 8 + j) * KQ + nbase + ny * 4);
        #pragma unroll
        for (int i = 0; i < 4; ++i) {
            const int n = ny * 4 + i;
            const int phys = ko ^ (n & 15);      // 16-chunk XOR swizzle (j-invariant on read)
            short8 w;
            #pragma unroll
            for (int j = 0; j < 8; ++j)
                w[j] = (short)f2bf(((const float*)&v[j])[i]);
            *(short8*)&Bl[n * DDIM + phys * 8] = w;
        }
    }
    __syncthreads();   // the ONLY barrier

    // per-lane B byte offsets per k-step s (j adds an immediate 8192)
    int vbo[8];
    #pragma unroll
    for (int s = 0; s < 8; ++s)
        vbo[s] = wc * 32768 + l15 * 512 + (((4 * s + quad) ^ l15) * 16);

    for (int g = 0; g < 8; ++g) {
        const int rb = g * 4 + wr;       // 32-row block, 0..31

        // A fragments straight from global (L2-resident): 2 x 8 x b128
        short8 af[2][8];
        #pragma unroll
        for (int i = 0; i < 2; ++i) {
            const unsigned short* ap = Ab + (size_t)(rb * 32 + i * 16 + l15) * DDIM + quad * 8;
            #pragma unroll
            for (int s = 0; s < 8; ++s)
                af[i][s] = *(const short8*)(ap + s * 32);
        }

        floatx4 acc[2][4] = {};
        #pragma unroll
        for (int s = 0; s < 8; ++s) {
            #pragma unroll
            for (int j = 0; j < 4; ++j) {
                const short8 bf = *(const short8*)((const char*)Bl + vbo[s] + j * 8192);
                acc[0][j] = __builtin_amdgcn_mfma_f32_16x16x32_bf16(af[0][s], bf, acc[0][j], 0, 0, 0);
                acc[1][j] = __builtin_amdgcn_mfma_f32_16x16x32_bf16(af[1][s], bf, acc[1][j], 0, 0, 0);
            }
        }

        // epilogue: base-2 logits. C layout: col=lane&15, row=quad*4+reg (verified).
        #pragma unroll
        for (int i = 0; i < 2; ++i) {
            #pragma unroll
            for (int r = 0; r < 4; ++r) {
                float mx = fmaxf(fmaxf(acc[i][0][r], acc[i][1][r]),
                                 fmaxf(acc[i][2][r], acc[i][3][r]));
                mx = fmaxf(mx, __shfl_xor(mx, 1, 64));
                mx = fmaxf(mx, __shfl_xor(mx, 2, 64));
                mx = fmaxf(mx, __shfl_xor(mx, 4, 64));
                mx = fmaxf(mx, __shfl_xor(mx, 8, 64));
                float s2 = 0.f;
                #pragma unroll
                for (int j = 0; j < 4; ++j)
                    s2 += __builtin_amdgcn_exp2f(acc[i][j][r] - mx);
                s2 += __shfl_xor(s2, 1, 64);
                s2 += __shfl_xor(s2, 2, 64);
                s2 += __shfl_xor(s2, 4, 64);
                s2 += __shfl_xor(s2, 8, 64);
                if (l15 == 0) {
                    const int row = rb * 32 + i * 16 + quad * 4 + r;
                    partials[(size_t)row * NPART + nb * 2 + wc] = make_float2(mx, s2);
                }
            }
        }
    }
}

// ---- per-row combine + positive logit + atomic mean ----
__global__ __launch_bounds__(256)
void finalize_rows(const float2* __restrict__ partials,
                   const float* __restrict__ online,
                   const float* __restrict__ mom,
                   const float* __restrict__ temp,
                   float* __restrict__ out)
{
    const int n = blockIdx.x;
    const int t = threadIdx.x;
    __shared__ float redA[4], redB[4], redC[4];

    const float inv_t = 1.0f / temp[0];

    float2 p[4];
    #pragma unroll
    for (int i = 0; i < 4; ++i)
        p[i] = partials[(size_t)n * NPART + t + i * 256];

    float m = fmaxf(fmaxf(p[0].x, p[1].x), fmaxf(p[2].x, p[3].x));
    #pragma unroll
    for (int off = 1; off < 64; off <<= 1) m = fmaxf(m, __shfl_xor(m, off, 64));
    if ((t & 63) == 0) redA[t >> 6] = m;
    __syncthreads();
    const float M = fmaxf(fmaxf(redA[0], redA[1]), fmaxf(redA[2], redA[3]));

    float s = 0.f;
    #pragma unroll
    for (int i = 0; i < 4; ++i) s += p[i].y * __builtin_amdgcn_exp2f(p[i].x - M);
    #pragma unroll
    for (int off = 1; off < 64; off <<= 1) s += __shfl_xor(s, off, 64);
    if ((t & 63) == 0) redB[t >> 6] = s;

    float pv = online[(size_t)n * DDIM + t] * mom[(size_t)n * DDIM + t];
    #pragma unroll
    for (int off = 1; off < 64; off <<= 1) pv += __shfl_xor(pv, off, 64);
    if ((t & 63) == 0) redC[t >> 6] = pv;
    __syncthreads();

    if (t == 0) {
        const float S    = redB[0] + redB[1] + redB[2] + redB[3];
        const float pos2 = (redC[0] + redC[1] + redC[2] + redC[3]) * inv_t * (1.0f / LN2_F);
        const float M2   = fmaxf(M, pos2);
        const float L    = S * __builtin_amdgcn_exp2f(M - M2) + __builtin_amdgcn_exp2f(pos2 - M2);
        const float row  = M2 + __builtin_amdgcn_logf(L) - pos2;   // log2-domain lse - pos
        atomicAdd(out, row * (LN2_F / (float)NROWS));
    }
}

extern "C" void kernel_launch(void* const* d_in, const int* in_sizes, int n_in,
                              void* d_out, int out_size, void* d_ws, size_t ws_size,
                              hipStream_t stream)
{
    const float* online = (const float*)d_in[0];   // [1024][256]
    const float* mom    = (const float*)d_in[1];   // [1024][256]
    const float* queue  = (const float*)d_in[2];   // [256][65536]
    const float* temp   = (const float*)d_in[3];   // [1]
    float* out = (float*)d_out;

    // ws: Ab bf16 [1024][256] (512 KB) | partials float2 [1024][1024] (8 MB)
    char* ws = (char*)d_ws;
    unsigned short* Ab = (unsigned short*)ws;
    float2* partials   = (float2*)(ws + 524288);

    hipMemsetAsync(out, 0, sizeof(float), stream);
    conv_a<<<256, 256, 0, stream>>>(online, temp, Ab);
    gemm_softmax<<<KQ / BN, 512, 0, stream>>>(Ab, queue, partials);
    finalize_rows<<<NROWS, 256, 0, stream>>>(partials, online, mom, temp, out);
}

// Round 5
// 256.166 us; speedup vs baseline: 1.0051x; 1.0051x over previous
//
#include <hip/hip_runtime.h>
#include <hip/hip_bf16.h>

// loss = mean_n( logsumexp([pos_n, (online@queue)_n]/t) - pos_n/t )   (fwd: alpha mix = identity)
// v5 = v4 with ext_vector types for nontemporal builtins (compile fix).
//     nt loads for Q, nt stores for partials, partials [part][row] coalesced,
//     pos-dot fused into conv_a, base-2 softmax, one barrier in gemm.

#define NROWS 1024
#define DDIM  256
#define KQ    65536
#define BN    128
#define NPART 1024
#define LN2_F 0.69314718055994531f

typedef short  short8  __attribute__((ext_vector_type(8)));
typedef float  floatx4 __attribute__((ext_vector_type(4)));

__device__ __forceinline__ unsigned short f2bf(float f) {
    unsigned int u = __float_as_uint(f);
    u += 0x7FFFu + ((u >> 16) & 1u);   // RNE
    return (unsigned short)(u >> 16);
}

// ---- A conversion (bf16(A/(t*ln2))) + fused positive-pair dot (one wave per row) ----
__global__ __launch_bounds__(256)
void conv_a(const float* __restrict__ A, const float* __restrict__ mom,
            const float* __restrict__ temp,
            unsigned short* __restrict__ Ab, float* __restrict__ pos2)
{
    const float s = 1.0f / (temp[0] * LN2_F);
    const int i = blockIdx.x * 256 + threadIdx.x;       // global float4 index, 64 per row
    const floatx4 v = ((const floatx4*)A)[i];
    ushort4 w;
    w.x = f2bf(v.x * s); w.y = f2bf(v.y * s);
    w.z = f2bf(v.z * s); w.w = f2bf(v.w * s);
    ((ushort4*)Ab)[i] = w;

    const floatx4 m = ((const floatx4*)mom)[i];
    float d = v.x * m.x + v.y * m.y + v.z * m.z + v.w * m.w;
    d += __shfl_xor(d, 1, 64);
    d += __shfl_xor(d, 2, 64);
    d += __shfl_xor(d, 4, 64);
    d += __shfl_xor(d, 8, 64);
    d += __shfl_xor(d, 16, 64);
    d += __shfl_xor(d, 32, 64);
    if ((threadIdx.x & 63) == 0)
        pos2[i >> 6] = d * s;          // base-2-domain positive logit
}

// ---- fused GEMM + online-softmax partials. Grid: 512 blocks (one 128-col stripe each) ----
__global__ __launch_bounds__(512, 4)
void gemm_softmax(const unsigned short* __restrict__ Ab,   // [1024][256] bf16, pre-scaled
                  const float* __restrict__ Q,             // [256][65536] fp32
                  float2* __restrict__ partials)           // [NPART][1024]  (part-major!)
{
    __shared__ __align__(16) unsigned short Bl[BN * DDIM];   // [n][k] bf16, 64 KB, swizzled

    const int tid  = threadIdx.x;
    const int lane = tid & 63;
    const int wave = tid >> 6;          // 0..7
    const int wc   = wave & 1;          // 64-col band
    const int wr   = wave >> 1;         // 0..3 row-wave
    const int l15  = lane & 15;
    const int quad = lane >> 4;
    const int nb   = blockIdx.x;        // 0..511
    const int nbase = nb * BN;

    // ---- stage B once: Q[k][nbase..+127] fp32 -> Bl[n][k] bf16 (register transpose) ----
    // nt loads: Q is streamed exactly once; keep it out of L2 so Ab stays resident.
    #pragma unroll
    for (int iter = 0; iter < 2; ++iter) {
        const int t2 = iter * 512 + tid;
        const int ny = t2 & 31;          // n-quad (4 cols)
        const int ko = t2 >> 5;          // k-octet (8 rows), 0..31
        floatx4 v[8];
        #pragma unroll
        for (int j = 0; j < 8; ++j)
            v[j] = __builtin_nontemporal_load(
                       (const floatx4*)(Q + (size_t)(ko * 8 + j) * KQ + nbase + ny * 4));
        #pragma unroll
        for (int i = 0; i < 4; ++i) {
            const int n = ny * 4 + i;
            const int phys = ko ^ (n & 15);      // 16-chunk XOR swizzle (j-invariant on read)
            short8 w;
            #pragma unroll
            for (int j = 0; j < 8; ++j)
                w[j] = (short)f2bf(v[j][i]);
            *(short8*)&Bl[n * DDIM + phys * 8] = w;
        }
    }
    __syncthreads();   // the ONLY barrier

    // per-lane B byte offsets per k-step s (j adds an immediate 8192)
    int vbo[8];
    #pragma unroll
    for (int s = 0; s < 8; ++s)
        vbo[s] = wc * 32768 + l15 * 512 + (((4 * s + quad) ^ l15) * 16);

    for (int g = 0; g < 8; ++g) {
        const int rb = g * 4 + wr;       // 32-row block, 0..31

        // A fragments from global (L2-resident after nt fix): 2 x 8 x b128
        short8 af[2][8];
        #pragma unroll
        for (int i = 0; i < 2; ++i) {
            const unsigned short* ap = Ab + (size_t)(rb * 32 + i * 16 + l15) * DDIM + quad * 8;
            #pragma unroll
            for (int s = 0; s < 8; ++s)
                af[i][s] = *(const short8*)(ap + s * 32);
        }

        floatx4 acc[2][4] = {};
        #pragma unroll
        for (int s = 0; s < 8; ++s) {
            #pragma unroll
            for (int j = 0; j < 4; ++j) {
                const short8 bf = *(const short8*)((const char*)Bl + vbo[s] + j * 8192);
                acc[0][j] = __builtin_amdgcn_mfma_f32_16x16x32_bf16(af[0][s], bf, acc[0][j], 0, 0, 0);
                acc[1][j] = __builtin_amdgcn_mfma_f32_16x16x32_bf16(af[1][s], bf, acc[1][j], 0, 0, 0);
            }
        }

        // epilogue: base-2 logits. C layout: col=lane&15, row=quad*4+reg (verified).
        #pragma unroll
        for (int i = 0; i < 2; ++i) {
            float2 tmp[4];
            #pragma unroll
            for (int r = 0; r < 4; ++r) {
                float mx = fmaxf(fmaxf(acc[i][0][r], acc[i][1][r]),
                                 fmaxf(acc[i][2][r], acc[i][3][r]));
                mx = fmaxf(mx, __shfl_xor(mx, 1, 64));
                mx = fmaxf(mx, __shfl_xor(mx, 2, 64));
                mx = fmaxf(mx, __shfl_xor(mx, 4, 64));
                mx = fmaxf(mx, __shfl_xor(mx, 8, 64));
                float s2 = 0.f;
                #pragma unroll
                for (int j = 0; j < 4; ++j)
                    s2 += __builtin_amdgcn_exp2f(acc[i][j][r] - mx);
                s2 += __shfl_xor(s2, 1, 64);
                s2 += __shfl_xor(s2, 2, 64);
                s2 += __shfl_xor(s2, 4, 64);
                s2 += __shfl_xor(s2, 8, 64);
                tmp[r] = make_float2(mx, s2);
            }
            if (l15 == 0) {
                // coalesced: 4 writer lanes (quad 0..3) cover 128 contiguous bytes
                const int pn  = nb * 2 + wc;
                const int row = rb * 32 + i * 16 + quad * 4;
                floatx4* dst = (floatx4*)(partials + (size_t)pn * NROWS + row);
                floatx4 w0 = {tmp[0].x, tmp[0].y, tmp[1].x, tmp[1].y};
                floatx4 w1 = {tmp[2].x, tmp[2].y, tmp[3].x, tmp[3].y};
                __builtin_nontemporal_store(w0, dst);
                __builtin_nontemporal_store(w1, dst + 1);
            }
        }
    }
}

// ---- combine partials per row + positive logit + atomic mean ----
// Grid: 64 blocks x 256 threads. Block owns 16 rows; 16 part-groups of 64 parts.
__global__ __launch_bounds__(256)
void finalize_rows(const float2* __restrict__ partials,   // [NPART][1024]
                   const float* __restrict__ pos2,
                   float* __restrict__ out)
{
    const int t   = threadIdx.x;
    const int rl  = t & 15;              // row within block
    const int grp = t >> 4;              // part group 0..15
    const int row = blockIdx.x * 16 + rl;

    float M = -3.0e38f, S = 0.f;
    #pragma unroll 1
    for (int pb = 0; pb < 64; pb += 8) {
        float2 v[8];
        #pragma unroll
        for (int j = 0; j < 8; ++j)
            v[j] = partials[(size_t)(grp * 64 + pb + j) * NROWS + row];
        #pragma unroll
        for (int j = 0; j < 8; ++j) {
            const float M2 = fmaxf(M, v[j].x);
            S = S * __builtin_amdgcn_exp2f(M - M2) + v[j].y * __builtin_amdgcn_exp2f(v[j].x - M2);
            M = M2;
        }
    }

    __shared__ float2 sm[16][17];
    sm[grp][rl] = make_float2(M, S);
    __syncthreads();

    if (t < 64) {
        float val = 0.f;
        if (t < 16) {
            float Mm = -3.0e38f, Ss = 0.f;
            #pragma unroll
            for (int g2 = 0; g2 < 16; ++g2) {
                const float2 v = sm[g2][t];
                const float M2 = fmaxf(Mm, v.x);
                Ss = Ss * __builtin_amdgcn_exp2f(Mm - M2) + v.y * __builtin_amdgcn_exp2f(v.x - M2);
                Mm = M2;
            }
            const float p  = pos2[blockIdx.x * 16 + t];
            const float M2 = fmaxf(Mm, p);
            const float L  = Ss * __builtin_amdgcn_exp2f(Mm - M2) + __builtin_amdgcn_exp2f(p - M2);
            val = (M2 + __builtin_amdgcn_logf(L) - p) * LN2_F;   // log2-domain lse - pos, back to ln
        }
        val += __shfl_xor(val, 1, 64);
        val += __shfl_xor(val, 2, 64);
        val += __shfl_xor(val, 4, 64);
        val += __shfl_xor(val, 8, 64);
        val += __shfl_xor(val, 16, 64);
        val += __shfl_xor(val, 32, 64);
        if (t == 0) atomicAdd(out, val * (1.0f / (float)NROWS));
    }
}

extern "C" void kernel_launch(void* const* d_in, const int* in_sizes, int n_in,
                              void* d_out, int out_size, void* d_ws, size_t ws_size,
                              hipStream_t stream)
{
    const float* online = (const float*)d_in[0];   // [1024][256]
    const float* mom    = (const float*)d_in[1];   // [1024][256]
    const float* queue  = (const float*)d_in[2];   // [256][65536]
    const float* temp   = (const float*)d_in[3];   // [1]
    float* out = (float*)d_out;

    // ws: Ab bf16 [1024][256] (512 KB) | partials float2 [1024][1024] (8 MB) | pos2 [1024] (4 KB)
    char* ws = (char*)d_ws;
    unsigned short* Ab = (unsigned short*)ws;
    float2* partials   = (float2*)(ws + 524288);
    float*  pos2       = (float*)(ws + 524288 + 8388608);

    (void)hipMemsetAsync(out, 0, sizeof(float), stream);
    conv_a<<<256, 256, 0, stream>>>(online, mom, temp, Ab, pos2);
    gemm_softmax<<<KQ / BN, 512, 0, stream>>>(Ab, queue, partials);
    finalize_rows<<<64, 256, 0, stream>>>(partials, pos2, out);
}

// Round 6
// 225.168 us; speedup vs baseline: 1.1435x; 1.1377x over previous
//
#include <hip/hip_runtime.h>
#include <hip/hip_bf16.h>

// loss = mean_n( logsumexp([pos_n, (online@queue)_n]/t) - pos_n/t )   (fwd: alpha mix = identity)
// v6: spill fix + reuse reshape. 256-thr blocks (4 waves), wave tile 64 rows x 128 cols:
//     acc[4][8] in AGPR, af[4] per-k-step from L2, bf[8] from LDS. 2 blocks/CU.
//     Q staged once per stripe (nt loads, register transpose, XOR-swizzled LDS).

#define NROWS 1024
#define DDIM  256
#define KQ    65536
#define BN    128
#define NPART 512
#define LN2_F 0.69314718055994531f

typedef short  short8  __attribute__((ext_vector_type(8)));
typedef float  floatx4 __attribute__((ext_vector_type(4)));

__device__ __forceinline__ unsigned short f2bf(float f) {
    unsigned int u = __float_as_uint(f);
    u += 0x7FFFu + ((u >> 16) & 1u);   // RNE
    return (unsigned short)(u >> 16);
}

// ---- A conversion (bf16(A/(t*ln2))) + fused positive-pair dot (one wave per row) ----
__global__ __launch_bounds__(256)
void conv_a(const float* __restrict__ A, const float* __restrict__ mom,
            const float* __restrict__ temp,
            unsigned short* __restrict__ Ab, float* __restrict__ pos2)
{
    const float s = 1.0f / (temp[0] * LN2_F);
    const int i = blockIdx.x * 256 + threadIdx.x;       // global float4 index, 64 per row
    const floatx4 v = ((const floatx4*)A)[i];
    ushort4 w;
    w.x = f2bf(v.x * s); w.y = f2bf(v.y * s);
    w.z = f2bf(v.z * s); w.w = f2bf(v.w * s);
    ((ushort4*)Ab)[i] = w;

    const floatx4 m = ((const floatx4*)mom)[i];
    float d = v.x * m.x + v.y * m.y + v.z * m.z + v.w * m.w;
    d += __shfl_xor(d, 1, 64);
    d += __shfl_xor(d, 2, 64);
    d += __shfl_xor(d, 4, 64);
    d += __shfl_xor(d, 8, 64);
    d += __shfl_xor(d, 16, 64);
    d += __shfl_xor(d, 32, 64);
    if ((threadIdx.x & 63) == 0)
        pos2[i >> 6] = d * s;          // base-2-domain positive logit
}

// ---- fused GEMM + online-softmax partials. 512 blocks x 256 thr; block = one 128-col stripe ----
__global__ __launch_bounds__(256, 2)
void gemm_softmax(const unsigned short* __restrict__ Ab,   // [1024][256] bf16, pre-scaled
                  const float* __restrict__ Q,             // [256][65536] fp32
                  float2* __restrict__ partials)           // [NPART][1024]  (part-major)
{
    __shared__ __align__(16) unsigned short Bl[BN * DDIM];   // [n][k] bf16, 64 KB, swizzled

    const int tid  = threadIdx.x;
    const int lane = tid & 63;
    const int wave = tid >> 6;          // 0..3
    const int l15  = lane & 15;
    const int quad = lane >> 4;
    const int nb   = blockIdx.x;        // 0..511
    const int nbase = nb * BN;

    // ---- stage B once: Q[k][nbase..+127] fp32 -> Bl[n][k] bf16 (register transpose) ----
    #pragma unroll
    for (int iter = 0; iter < 4; ++iter) {
        const int t2 = iter * 256 + tid;    // 1024 tasks
        const int ny = t2 & 31;             // n-quad (4 cols)
        const int ko = t2 >> 5;             // k-octet (8 rows), 0..31
        floatx4 v[8];
        #pragma unroll
        for (int j = 0; j < 8; ++j)
            v[j] = __builtin_nontemporal_load(
                       (const floatx4*)(Q + (size_t)(ko * 8 + j) * KQ + nbase + ny * 4));
        #pragma unroll
        for (int i2 = 0; i2 < 4; ++i2) {
            const int n = ny * 4 + i2;
            const int phys = ko ^ (n & 15);      // 16B-chunk XOR swizzle
            short8 w;
            #pragma unroll
            for (int j = 0; j < 8; ++j)
                w[j] = (short)f2bf(v[j][i2]);
            *(short8*)&Bl[n * DDIM + phys * 8] = w;
        }
    }
    __syncthreads();   // the ONLY barrier

    // per-s LDS byte base (j adds an immediate j*8192)
    int vbo[8];
    #pragma unroll
    for (int s = 0; s < 8; ++s)
        vbo[s] = l15 * 512 + (((4 * s + quad) ^ l15) * 16);

    for (int g = 0; g < 4; ++g) {
        const int rowbase = g * 256 + wave * 64;

        floatx4 acc[4][8] = {};
        #pragma unroll
        for (int s = 0; s < 8; ++s) {
            short8 af[4];
            #pragma unroll
            for (int i = 0; i < 4; ++i)
                af[i] = *(const short8*)(Ab + (size_t)(rowbase + i * 16 + l15) * DDIM
                                            + quad * 8 + s * 32);
            short8 bfv[8];
            #pragma unroll
            for (int j = 0; j < 8; ++j)
                bfv[j] = *(const short8*)((const char*)Bl + vbo[s] + j * 8192);
            #pragma unroll
            for (int i = 0; i < 4; ++i)
                #pragma unroll
                for (int j = 0; j < 8; ++j)
                    acc[i][j] = __builtin_amdgcn_mfma_f32_16x16x32_bf16(af[i], bfv[j], acc[i][j], 0, 0, 0);
        }

        // epilogue: base-2 logits. C layout: col(n) = lane&15, row(m) = quad*4+reg (verified).
        // Reduce over all 128 stripe cols: 8 j-regs + shfl over l15 bits.
        #pragma unroll
        for (int i = 0; i < 4; ++i) {
            float2 tmp[4];
            #pragma unroll
            for (int r = 0; r < 4; ++r) {
                float mx = acc[i][0][r];
                #pragma unroll
                for (int j = 1; j < 8; ++j) mx = fmaxf(mx, acc[i][j][r]);
                mx = fmaxf(mx, __shfl_xor(mx, 1, 64));
                mx = fmaxf(mx, __shfl_xor(mx, 2, 64));
                mx = fmaxf(mx, __shfl_xor(mx, 4, 64));
                mx = fmaxf(mx, __shfl_xor(mx, 8, 64));
                float s2 = 0.f;
                #pragma unroll
                for (int j = 0; j < 8; ++j)
                    s2 += __builtin_amdgcn_exp2f(acc[i][j][r] - mx);
                s2 += __shfl_xor(s2, 1, 64);
                s2 += __shfl_xor(s2, 2, 64);
                s2 += __shfl_xor(s2, 4, 64);
                s2 += __shfl_xor(s2, 8, 64);
                tmp[r] = make_float2(mx, s2);
            }
            if (l15 == 0) {
                // 4 quad-leader lanes cover 128 contiguous bytes
                const int row = rowbase + i * 16 + quad * 4;
                floatx4* dst = (floatx4*)(partials + (size_t)nb * NROWS + row);
                floatx4 w0 = {tmp[0].x, tmp[0].y, tmp[1].x, tmp[1].y};
                floatx4 w1 = {tmp[2].x, tmp[2].y, tmp[3].x, tmp[3].y};
                __builtin_nontemporal_store(w0, dst);
                __builtin_nontemporal_store(w1, dst + 1);
            }
        }
    }
}

// ---- combine partials per row + positive logit + atomic mean ----
// Grid: 64 blocks x 256 threads. Block owns 16 rows; 16 part-groups of 32 parts.
__global__ __launch_bounds__(256)
void finalize_rows(const float2* __restrict__ partials,   // [NPART][1024]
                   const float* __restrict__ pos2,
                   float* __restrict__ out)
{
    const int t   = threadIdx.x;
    const int rl  = t & 15;              // row within block
    const int grp = t >> 4;              // part group 0..15
    const int row = blockIdx.x * 16 + rl;

    float M = -3.0e38f, S = 0.f;
    #pragma unroll 1
    for (int pb = 0; pb < 32; pb += 8) {
        float2 v[8];
        #pragma unroll
        for (int j = 0; j < 8; ++j)
            v[j] = partials[(size_t)(grp * 32 + pb + j) * NROWS + row];
        #pragma unroll
        for (int j = 0; j < 8; ++j) {
            const float M2 = fmaxf(M, v[j].x);
            S = S * __builtin_amdgcn_exp2f(M - M2) + v[j].y * __builtin_amdgcn_exp2f(v[j].x - M2);
            M = M2;
        }
    }

    __shared__ float2 sm[16][17];
    sm[grp][rl] = make_float2(M, S);
    __syncthreads();

    if (t < 64) {
        float val = 0.f;
        if (t < 16) {
            float Mm = -3.0e38f, Ss = 0.f;
            #pragma unroll
            for (int g2 = 0; g2 < 16; ++g2) {
                const float2 v = sm[g2][t];
                const float M2 = fmaxf(Mm, v.x);
                Ss = Ss * __builtin_amdgcn_exp2f(Mm - M2) + v.y * __builtin_amdgcn_exp2f(v.x - M2);
                Mm = M2;
            }
            const float p  = pos2[blockIdx.x * 16 + t];
            const float M2 = fmaxf(Mm, p);
            const float L  = Ss * __builtin_amdgcn_exp2f(Mm - M2) + __builtin_amdgcn_exp2f(p - M2);
            val = (M2 + __builtin_amdgcn_logf(L) - p) * LN2_F;   // back to natural log
        }
        val += __shfl_xor(val, 1, 64);
        val += __shfl_xor(val, 2, 64);
        val += __shfl_xor(val, 4, 64);
        val += __shfl_xor(val, 8, 64);
        val += __shfl_xor(val, 16, 64);
        val += __shfl_xor(val, 32, 64);
        if (t == 0) atomicAdd(out, val * (1.0f / (float)NROWS));
    }
}

extern "C" void kernel_launch(void* const* d_in, const int* in_sizes, int n_in,
                              void* d_out, int out_size, void* d_ws, size_t ws_size,
                              hipStream_t stream)
{
    const float* online = (const float*)d_in[0];   // [1024][256]
    const float* mom    = (const float*)d_in[1];   // [1024][256]
    const float* queue  = (const float*)d_in[2];   // [256][65536]
    const float* temp   = (const float*)d_in[3];   // [1]
    float* out = (float*)d_out;

    // ws: Ab bf16 [1024][256] (512 KB) | partials float2 [512][1024] (4 MB) | pos2 [1024] (4 KB)
    char* ws = (char*)d_ws;
    unsigned short* Ab = (unsigned short*)ws;
    float2* partials   = (float2*)(ws + 524288);
    float*  pos2       = (float*)(ws + 524288 + 4194304);

    (void)hipMemsetAsync(out, 0, sizeof(float), stream);
    conv_a<<<256, 256, 0, stream>>>(online, mom, temp, Ab, pos2);
    gemm_softmax<<<KQ / BN, 256, 0, stream>>>(Ab, queue, partials);
    finalize_rows<<<64, 256, 0, stream>>>(partials, pos2, out);
}

// Round 7
// 158.212 us; speedup vs baseline: 1.6274x; 1.4232x over previous
//
#include <hip/hip_runtime.h>
#include <hip/hip_bf16.h>

// loss = mean_n( logsumexp([pos_n, (online@queue)_n]/t) - pos_n/t )   (fwd: alpha mix = identity)
// v7 = v6 + spill fix: #pragma unroll 1 on g-loop and s-loop (v6's full unroll created
//     4 live copies of acc[4][8] = 512 regs -> 110 MB scratch traffic). Manual one-step
//     A prefetch inside the s-loop; LDS offsets computed inline (no reg-array indexing).

#define NROWS 1024
#define DDIM  256
#define KQ    65536
#define BN    128
#define NPART 512
#define LN2_F 0.69314718055994531f

typedef short  short8  __attribute__((ext_vector_type(8)));
typedef float  floatx4 __attribute__((ext_vector_type(4)));

__device__ __forceinline__ unsigned short f2bf(float f) {
    unsigned int u = __float_as_uint(f);
    u += 0x7FFFu + ((u >> 16) & 1u);   // RNE
    return (unsigned short)(u >> 16);
}

// ---- A conversion (bf16(A/(t*ln2))) + fused positive-pair dot (one wave per row) ----
__global__ __launch_bounds__(256)
void conv_a(const float* __restrict__ A, const float* __restrict__ mom,
            const float* __restrict__ temp,
            unsigned short* __restrict__ Ab, float* __restrict__ pos2)
{
    const float s = 1.0f / (temp[0] * LN2_F);
    const int i = blockIdx.x * 256 + threadIdx.x;       // global float4 index, 64 per row
    const floatx4 v = ((const floatx4*)A)[i];
    ushort4 w;
    w.x = f2bf(v.x * s); w.y = f2bf(v.y * s);
    w.z = f2bf(v.z * s); w.w = f2bf(v.w * s);
    ((ushort4*)Ab)[i] = w;

    const floatx4 m = ((const floatx4*)mom)[i];
    float d = v.x * m.x + v.y * m.y + v.z * m.z + v.w * m.w;
    d += __shfl_xor(d, 1, 64);
    d += __shfl_xor(d, 2, 64);
    d += __shfl_xor(d, 4, 64);
    d += __shfl_xor(d, 8, 64);
    d += __shfl_xor(d, 16, 64);
    d += __shfl_xor(d, 32, 64);
    if ((threadIdx.x & 63) == 0)
        pos2[i >> 6] = d * s;          // base-2-domain positive logit
}

// ---- fused GEMM + online-softmax partials. 512 blocks x 256 thr; block = one 128-col stripe ----
__global__ __launch_bounds__(256, 2)
void gemm_softmax(const unsigned short* __restrict__ Ab,   // [1024][256] bf16, pre-scaled
                  const float* __restrict__ Q,             // [256][65536] fp32
                  float2* __restrict__ partials)           // [NPART][1024]  (part-major)
{
    __shared__ __align__(16) unsigned short Bl[BN * DDIM];   // [n][k] bf16, 64 KB, swizzled

    const int tid  = threadIdx.x;
    const int lane = tid & 63;
    const int wave = tid >> 6;          // 0..3
    const int l15  = lane & 15;
    const int quad = lane >> 4;
    const int nb   = blockIdx.x;        // 0..511
    const int nbase = nb * BN;

    // ---- stage B once: Q[k][nbase..+127] fp32 -> Bl[n][k] bf16 (register transpose) ----
    #pragma unroll
    for (int iter = 0; iter < 4; ++iter) {
        const int t2 = iter * 256 + tid;    // 1024 tasks
        const int ny = t2 & 31;             // n-quad (4 cols)
        const int ko = t2 >> 5;             // k-octet (8 rows), 0..31
        floatx4 v[8];
        #pragma unroll
        for (int j = 0; j < 8; ++j)
            v[j] = __builtin_nontemporal_load(
                       (const floatx4*)(Q + (size_t)(ko * 8 + j) * KQ + nbase + ny * 4));
        #pragma unroll
        for (int i2 = 0; i2 < 4; ++i2) {
            const int n = ny * 4 + i2;
            const int phys = ko ^ (n & 15);      // 16B-chunk XOR swizzle
            short8 w;
            #pragma unroll
            for (int j = 0; j < 8; ++j)
                w[j] = (short)f2bf(v[j][i2]);
            *(short8*)&Bl[n * DDIM + phys * 8] = w;
        }
    }
    __syncthreads();   // the ONLY barrier

    #pragma unroll 1
    for (int g = 0; g < 4; ++g) {
        const int rowbase = g * 256 + wave * 64;
        const unsigned short* apb = Ab + (size_t)(rowbase + l15) * DDIM + quad * 8;

        floatx4 acc[4][8] = {};
        short8 af[4];
        #pragma unroll
        for (int i = 0; i < 4; ++i)
            af[i] = *(const short8*)(apb + i * 16 * DDIM);

        #pragma unroll 1
        for (int s = 0; s < 8; ++s) {
            // prefetch next k-step's A fragments (wrap at s=7; harmless reload)
            const int sn = (s + 1) & 7;
            short8 afn[4];
            #pragma unroll
            for (int i = 0; i < 4; ++i)
                afn[i] = *(const short8*)(apb + i * 16 * DDIM + sn * 32);

            const int vb = l15 * 512 + (((4 * s + quad) ^ l15) * 16);
            short8 bfv[8];
            #pragma unroll
            for (int j = 0; j < 8; ++j)
                bfv[j] = *(const short8*)((const char*)Bl + vb + j * 8192);

            #pragma unroll
            for (int i = 0; i < 4; ++i)
                #pragma unroll
                for (int j = 0; j < 8; ++j)
                    acc[i][j] = __builtin_amdgcn_mfma_f32_16x16x32_bf16(af[i], bfv[j], acc[i][j], 0, 0, 0);

            #pragma unroll
            for (int i = 0; i < 4; ++i) af[i] = afn[i];
        }

        // epilogue: base-2 logits. C layout: col(n) = lane&15, row(m) = quad*4+reg (verified).
        #pragma unroll
        for (int i = 0; i < 4; ++i) {
            float2 tmp[4];
            #pragma unroll
            for (int r = 0; r < 4; ++r) {
                float mx = acc[i][0][r];
                #pragma unroll
                for (int j = 1; j < 8; ++j) mx = fmaxf(mx, acc[i][j][r]);
                mx = fmaxf(mx, __shfl_xor(mx, 1, 64));
                mx = fmaxf(mx, __shfl_xor(mx, 2, 64));
                mx = fmaxf(mx, __shfl_xor(mx, 4, 64));
                mx = fmaxf(mx, __shfl_xor(mx, 8, 64));
                float s2 = 0.f;
                #pragma unroll
                for (int j = 0; j < 8; ++j)
                    s2 += __builtin_amdgcn_exp2f(acc[i][j][r] - mx);
                s2 += __shfl_xor(s2, 1, 64);
                s2 += __shfl_xor(s2, 2, 64);
                s2 += __shfl_xor(s2, 4, 64);
                s2 += __shfl_xor(s2, 8, 64);
                tmp[r] = make_float2(mx, s2);
            }
            if (l15 == 0) {
                // 4 quad-leader lanes cover 128 contiguous bytes
                const int row = rowbase + i * 16 + quad * 4;
                floatx4* dst = (floatx4*)(partials + (size_t)nb * NROWS + row);
                floatx4 w0 = {tmp[0].x, tmp[0].y, tmp[1].x, tmp[1].y};
                floatx4 w1 = {tmp[2].x, tmp[2].y, tmp[3].x, tmp[3].y};
                __builtin_nontemporal_store(w0, dst);
                __builtin_nontemporal_store(w1, dst + 1);
            }
        }
    }
}

// ---- combine partials per row + positive logit + atomic mean ----
// Grid: 64 blocks x 256 threads. Block owns 16 rows; 16 part-groups of 32 parts.
__global__ __launch_bounds__(256)
void finalize_rows(const float2* __restrict__ partials,   // [NPART][1024]
                   const float* __restrict__ pos2,
                   float* __restrict__ out)
{
    const int t   = threadIdx.x;
    const int rl  = t & 15;              // row within block
    const int grp = t >> 4;              // part group 0..15
    const int row = blockIdx.x * 16 + rl;

    float M = -3.0e38f, S = 0.f;
    #pragma unroll 1
    for (int pb = 0; pb < 32; pb += 8) {
        float2 v[8];
        #pragma unroll
        for (int j = 0; j < 8; ++j)
            v[j] = partials[(size_t)(grp * 32 + pb + j) * NROWS + row];
        #pragma unroll
        for (int j = 0; j < 8; ++j) {
            const float M2 = fmaxf(M, v[j].x);
            S = S * __builtin_amdgcn_exp2f(M - M2) + v[j].y * __builtin_amdgcn_exp2f(v[j].x - M2);
            M = M2;
        }
    }

    __shared__ float2 sm[16][17];
    sm[grp][rl] = make_float2(M, S);
    __syncthreads();

    if (t < 64) {
        float val = 0.f;
        if (t < 16) {
            float Mm = -3.0e38f, Ss = 0.f;
            #pragma unroll
            for (int g2 = 0; g2 < 16; ++g2) {
                const float2 v = sm[g2][t];
                const float M2 = fmaxf(Mm, v.x);
                Ss = Ss * __builtin_amdgcn_exp2f(Mm - M2) + v.y * __builtin_amdgcn_exp2f(v.x - M2);
                Mm = M2;
            }
            const float p  = pos2[blockIdx.x * 16 + t];
            const float M2 = fmaxf(Mm, p);
            const float L  = Ss * __builtin_amdgcn_exp2f(Mm - M2) + __builtin_amdgcn_exp2f(p - M2);
            val = (M2 + __builtin_amdgcn_logf(L) - p) * LN2_F;   // back to natural log
        }
        val += __shfl_xor(val, 1, 64);
        val += __shfl_xor(val, 2, 64);
        val += __shfl_xor(val, 4, 64);
        val += __shfl_xor(val, 8, 64);
        val += __shfl_xor(val, 16, 64);
        val += __shfl_xor(val, 32, 64);
        if (t == 0) atomicAdd(out, val * (1.0f / (float)NROWS));
    }
}

extern "C" void kernel_launch(void* const* d_in, const int* in_sizes, int n_in,
                              void* d_out, int out_size, void* d_ws, size_t ws_size,
                              hipStream_t stream)
{
    const float* online = (const float*)d_in[0];   // [1024][256]
    const float* mom    = (const float*)d_in[1];   // [1024][256]
    const float* queue  = (const float*)d_in[2];   // [256][65536]
    const float* temp   = (const float*)d_in[3];   // [1]
    float* out = (float*)d_out;

    // ws: Ab bf16 [1024][256] (512 KB) | partials float2 [512][1024] (4 MB) | pos2 [1024] (4 KB)
    char* ws = (char*)d_ws;
    unsigned short* Ab = (unsigned short*)ws;
    float2* partials   = (float2*)(ws + 524288);
    float*  pos2       = (float*)(ws + 524288 + 4194304);

    (void)hipMemsetAsync(out, 0, sizeof(float), stream);
    conv_a<<<256, 256, 0, stream>>>(online, mom, temp, Ab, pos2);
    gemm_softmax<<<KQ / BN, 256, 0, stream>>>(Ab, queue, partials);
    finalize_rows<<<64, 256, 0, stream>>>(partials, pos2, out);
}